// Round 2
// baseline (428.592 us; speedup 1.0000x reference)
//
#include <hip/hip_runtime.h>
#include <hip/hip_bf16.h>
#include <stdint.h>

// Problem constants (from reference): B=64, T=32, J=128, N=64, IN_F=4096, OUT_F=256
#define Bv   64
#define Tv   32
#define Jv   128
#define Nv   64
#define Lv   256
#define INFv 4096

typedef __attribute__((ext_vector_type(8))) short  short8;   // 8 bf16 (4 VGPRs) — MFMA A/B frag
typedef __attribute__((ext_vector_type(4))) float  floatx4;  // MFMA C/D frag

// f32 -> bf16 bits, round-to-nearest-even (inputs are finite normals)
__device__ __forceinline__ unsigned int f2bf(float f) {
  union { float f; unsigned int u; } v; v.f = f;
  unsigned int r = v.u + 0x7fffu + ((v.u >> 16) & 1u);
  return r >> 16;
}

// Kernel A: transpose+convert full_weight [256][4096] f32 -> Wt [4096][256] bf16.
__global__ __launch_bounds__(256) void wt_transpose_kernel(
    const float* __restrict__ w, unsigned short* __restrict__ wt) {
  int i_base = blockIdx.x * 16;      // 256 blocks x 16 i-values
  int wave = threadIdx.x >> 6;
  int lane = threadIdx.x & 63;
  #pragma unroll
  for (int r = 0; r < 4; ++r) {
    int i = i_base + wave * 4 + r;
    unsigned int b0 = f2bf(w[(size_t)(4 * lane + 0) * INFv + i]);
    unsigned int b1 = f2bf(w[(size_t)(4 * lane + 1) * INFv + i]);
    unsigned int b2 = f2bf(w[(size_t)(4 * lane + 2) * INFv + i]);
    unsigned int b3 = f2bf(w[(size_t)(4 * lane + 3) * INFv + i]);
    uint2 u;
    u.x = b0 | (b1 << 16);
    u.y = b2 | (b3 << 16);
    *(uint2*)(wt + (size_t)i * Lv + 4 * lane) = u;
  }
}

// Main kernel v2: one block per (b,t). Y[j][l] computed as D = A·B with
//   A = G^T (M=l, K=n)  — from lB[l][n] swizzled LDS
//   B = X^T (K=n, N=j)  — from lA[j][n] swizzled LDS (B-frag: n=lane&15 -> j)
// D layout: col = lane&15 = j, row = qd*4+reg = l  -> lane holds 4 CONSECUTIVE l
// => float4 stores (16 B/lane), 4x fewer store instructions than v1.
// Single barrier: index loads are block-uniform (scalarized), no idxs[] LDS.
__global__ __launch_bounds__(256, 2) void masklin_kernel(
    const float* __restrict__ x, const int* __restrict__ idx,
    const unsigned short* __restrict__ wt, const float* __restrict__ wfull,
    int use_wt, float* __restrict__ y) {
  __shared__ __align__(16) unsigned short lA[Jv * Nv];  // 16 KB: [j][k] swizzled
  __shared__ __align__(16) unsigned short lB[Lv * Nv];  // 32 KB: [l][k] swizzled

  int bt = blockIdx.x;               // 0..2047
  int b = bt >> 5, t = bt & 31;
  int tid = threadIdx.x;
  int wave = tid >> 6, lane = tid & 63;

  // ---- stage A: X tile (128x64 f32, contiguous) -> bf16 swizzled LDS ----
  // swizzle: element (row,k) at row*64 + ((k>>3) ^ (row&7))*8 + (k&7)
  const float* xt = x + (size_t)(b * Tv + t) * (Jv * Nv);
  #pragma unroll
  for (int it = 0; it < 4; ++it) {
    int O = tid + it * 256;          // octet index: j = O>>3, chunk c = O&7
    int j = O >> 3, c = O & 7;
    const float4* p = (const float4*)(xt + (size_t)O * 8);
    float4 a0 = p[0], a1 = p[1];
    uint4 v;
    v.x = f2bf(a0.x) | (f2bf(a0.y) << 16);
    v.y = f2bf(a0.z) | (f2bf(a0.w) << 16);
    v.z = f2bf(a1.x) | (f2bf(a1.y) << 16);
    v.w = f2bf(a1.z) | (f2bf(a1.w) << 16);
    *(uint4*)&lA[j * 64 + ((c ^ (j & 7)) << 3)] = v;
  }

  // ---- stage B: gather G^T into lB[l][k=n] (transpose happens here) ----
  // indices[b][n][t] address is block-uniform -> compiler scalarizes (s_load).
  {
    const int* idxp = idx + ((size_t)b * Nv) * Tv + t;
    int l = tid;
    #pragma unroll
    for (int c = 0; c < 8; ++c) {
      unsigned int e[8];
      #pragma unroll
      for (int jj = 0; jj < 8; ++jj) {
        int n = c * 8 + jj;
        int in_row = idxp[(size_t)n * Tv];   // uniform load
        if (use_wt) {
          e[jj] = wt[(size_t)in_row * Lv + l];
        } else {
          e[jj] = f2bf(wfull[(size_t)l * INFv + in_row]);  // fallback: no ws
        }
      }
      uint4 v;
      v.x = e[0] | (e[1] << 16);
      v.y = e[2] | (e[3] << 16);
      v.z = e[4] | (e[5] << 16);
      v.w = e[6] | (e[7] << 16);
      *(uint4*)&lB[l * 64 + ((c ^ (l & 7)) << 3)] = v;
    }
  }
  __syncthreads();   // the ONLY barrier

  // ---- MFMA: wave w computes l in [64w, 64w+64) x all 128 j ----
  int m = lane & 15, qd = lane >> 4;
  floatx4 acc[4][8];                 // [lt][jt]
  #pragma unroll
  for (int lt = 0; lt < 4; ++lt)
    #pragma unroll
    for (int jt = 0; jt < 8; ++jt)
      acc[lt][jt] = (floatx4){0.f, 0.f, 0.f, 0.f};

  #pragma unroll
  for (int ks = 0; ks < 2; ++ks) {
    int chunk = ks * 4 + qd;         // k-chunk = (ks*32 + qd*8) >> 3
    short8 gfr[4], xfr[8];
    #pragma unroll
    for (int lt = 0; lt < 4; ++lt) {
      int l = wave * 64 + lt * 16 + m;        // A[m=lane&15 -> l][k=qd*8+j]
      gfr[lt] = *(const short8*)&lB[l * 64 + ((chunk ^ (l & 7)) << 3)];
    }
    #pragma unroll
    for (int jt = 0; jt < 8; ++jt) {
      int j = jt * 16 + m;                    // B[k=qd*8+j][n=lane&15 -> j]
      xfr[jt] = *(const short8*)&lA[j * 64 + ((chunk ^ (j & 7)) << 3)];
    }
    #pragma unroll
    for (int lt = 0; lt < 4; ++lt)
      #pragma unroll
      for (int jt = 0; jt < 8; ++jt)
        acc[lt][jt] = __builtin_amdgcn_mfma_f32_16x16x32_bf16(
            gfr[lt], xfr[jt], acc[lt][jt], 0, 0, 0);
  }

  // ---- epilogue: D col=lane&15=j, row=qd*4+r=l -> float4 along l ----
  float* yt = y + (size_t)(b * Tv + t) * (Jv * Lv);
  #pragma unroll
  for (int lt = 0; lt < 4; ++lt) {
    int l = wave * 64 + lt * 16 + qd * 4;
    #pragma unroll
    for (int jt = 0; jt < 8; ++jt) {
      int j = jt * 16 + m;
      *(floatx4*)(yt + (size_t)j * Lv + l) = acc[lt][jt];
    }
  }
}

extern "C" void kernel_launch(void* const* d_in, const int* in_sizes, int n_in,
                              void* d_out, int out_size, void* d_ws, size_t ws_size,
                              hipStream_t stream) {
  const float* x    = (const float*)d_in[0];
  const int*   idx  = (const int*)d_in[1];
  const float* w    = (const float*)d_in[2];
  float*       y    = (float*)d_out;

  const size_t wt_bytes = (size_t)INFv * Lv * sizeof(unsigned short);  // 2 MB
  int use_wt = (d_ws != nullptr && ws_size >= wt_bytes) ? 1 : 0;
  unsigned short* wt = (unsigned short*)d_ws;

  if (use_wt) {
    wt_transpose_kernel<<<256, 256, 0, stream>>>(w, wt);
  }
  masklin_kernel<<<Bv * Tv, 256, 0, stream>>>(x, idx, wt, w, use_wt, y);
}